// Round 1
// 869.631 us; speedup vs baseline: 1.6713x; 1.6713x over previous
//
#include <hip/hip_runtime.h>
#include <math.h>

#define TOK 16384
#define HD 7168
#define NE 256

typedef float f32x4 __attribute__((ext_vector_type(4)));
typedef __bf16 bfv8 __attribute__((ext_vector_type(8)));

constexpr int NTHR = 512;
constexpr int NK = HD / 32;      // 224 K-tiles of BK=32
// LDS geometry: per matrix region = 3 levels x 4 kb-groups x (128 rows x 16B + 256B pad)
constexpr int KBS  = 2304;       // kb stride (bytes); 144 slots == 16 mod 32 -> uniform 2-way banking (free)
constexpr int LVS  = 4 * KBS;    // 9216  level stride
constexpr int MATS = 3 * LVS;    // 27648 matrix region (A at 0, B at MATS)
constexpr int BUFS = 2 * MATS;   // 55296 per double-buffer half; total 108 KB

// RNE round of fp32 bits to bf16 (kept in high 16 bits). Carry into exponent is correct.
__device__ __forceinline__ unsigned rne_bf16_bits(float v) {
  unsigned u = __float_as_uint(v);
  return (u + 0x7FFFu + ((u >> 16) & 1u)) & 0xFFFF0000u;
}

// Split 8 consecutive fp32 (one 16B LDS entry per level) into 3 exact bf16 levels.
// Residuals are exact (Sterbenz); leftover <= 2^-27 |x|.
__device__ __forceinline__ void split8(const f32x4 lo, const f32x4 hi,
                                       int4& o0, int4& o1, int4& o2) {
  unsigned h0[8], h1[8], h2[8];
#pragma unroll
  for (int i = 0; i < 8; ++i) {
    float v = (i < 4) ? lo[i] : hi[i - 4];
    unsigned a0 = rne_bf16_bits(v);
    float r1 = v - __uint_as_float(a0);
    unsigned a1 = rne_bf16_bits(r1);
    float r2 = r1 - __uint_as_float(a1);
    unsigned a2 = rne_bf16_bits(r2);
    h0[i] = a0; h1[i] = a1; h2[i] = a2;
  }
  o0 = make_int4((int)((h0[0] >> 16) | (h0[1] & 0xFFFF0000u)),
                 (int)((h0[2] >> 16) | (h0[3] & 0xFFFF0000u)),
                 (int)((h0[4] >> 16) | (h0[5] & 0xFFFF0000u)),
                 (int)((h0[6] >> 16) | (h0[7] & 0xFFFF0000u)));
  o1 = make_int4((int)((h1[0] >> 16) | (h1[1] & 0xFFFF0000u)),
                 (int)((h1[2] >> 16) | (h1[3] & 0xFFFF0000u)),
                 (int)((h1[4] >> 16) | (h1[5] & 0xFFFF0000u)),
                 (int)((h1[6] >> 16) | (h1[7] & 0xFFFF0000u)));
  o2 = make_int4((int)((h2[0] >> 16) | (h2[1] & 0xFFFF0000u)),
                 (int)((h2[2] >> 16) | (h2[3] & 0xFFFF0000u)),
                 (int)((h2[4] >> 16) | (h2[5] & 0xFFFF0000u)),
                 (int)((h2[6] >> 16) | (h2[7] & 0xFFFF0000u)));
}

// Split-3 bf16 MFMA GEMM: C[t][e] = sum_k A[t][k] W[e][k], fp32-exact-class accuracy.
// Block 128x128, 8 waves (wave tile 64x32 = 4x2 tiles of 16x16x32 MFMA), BK=32,
// double-buffered LDS, register prefetch 2 tiles deep, one barrier per K-tile.
// Accuracy: product (0,0) -> Chi (flushed to Ctot every 16 tiles = K 512);
// cross products -> Clo (magnitude ~2^-9, own rounding negligible). Total ~2.5e-7 RMS.
__global__ __launch_bounds__(NTHR, 2)
void gemm_split3(const float* __restrict__ A, const float* __restrict__ W,
                 float* __restrict__ C) {
  __shared__ __align__(16) char lds[2 * BUFS];

  const int tid = threadIdx.x;
  const int lane = tid & 63;
  const int w = tid >> 6;
  const int wm = w >> 2;        // 0..1 : 64-row group
  const int wn = w & 3;         // 0..3 : 32-col group

  // XCD-chunked bijection (nwg=256): bm-pair (bn=0/1) lands on same XCD -> A slab L2-shared
  const int bb = blockIdx.x;
  const int wg = (bb & 7) * 32 + (bb >> 3);
  const int bm = wg >> 1, bn = wg & 1;

  const float* aBase = A + (size_t)bm * 128 * HD;
  const float* wBase = W + (size_t)bn * 128 * HD;

  // staging map: thread -> (row, 8 consecutive k); one full 16B LDS entry per level
  const int srow = tid >> 2;                   // 0..127
  const int sj = tid & 3;                      // kb group
  const size_t gOff = (size_t)srow * HD + sj * 8;
  const int wOff = sj * KBS + srow * 16;       // byte offset within a matrix region

  // fragment read bases (16x16x32: lane holds row=lane&15, k=(lane>>4)*8..+8 contiguous)
  const int frb = (lane >> 4) * KBS + (lane & 15) * 16;
  const int frbA = frb + wm * 64 * 16;             // + mt*256 + lv*LVS
  const int frbB = frb + MATS + wn * 32 * 16;      // + nt*256 + lv*LVS

  f32x4 Chi[4][2], Clo[4][2], Ctot[4][2];
#pragma unroll
  for (int mt = 0; mt < 4; ++mt)
#pragma unroll
    for (int nt = 0; nt < 2; ++nt) {
      Chi[mt][nt] = f32x4{0.f, 0.f, 0.f, 0.f};
      Clo[mt][nt] = f32x4{0.f, 0.f, 0.f, 0.f};
      Ctot[mt][nt] = f32x4{0.f, 0.f, 0.f, 0.f};
    }

  f32x4 rA0, rA1, rB0, rB1;

  // prologue: tile 0 -> buf0; tile 1 -> regs
  rA0 = *(const f32x4*)(aBase + gOff);
  rA1 = *(const f32x4*)(aBase + gOff + 4);
  rB0 = *(const f32x4*)(wBase + gOff);
  rB1 = *(const f32x4*)(wBase + gOff + 4);
  {
    int4 a0, a1, a2;
    split8(rA0, rA1, a0, a1, a2);
    char* d = lds + wOff;
    *(int4*)(d) = a0; *(int4*)(d + LVS) = a1; *(int4*)(d + 2 * LVS) = a2;
  }
  {
    int4 b0, b1, b2;
    split8(rB0, rB1, b0, b1, b2);
    char* d = lds + MATS + wOff;
    *(int4*)(d) = b0; *(int4*)(d + LVS) = b1; *(int4*)(d + 2 * LVS) = b2;
  }
  rA0 = *(const f32x4*)(aBase + gOff + 32);
  rA1 = *(const f32x4*)(aBase + gOff + 36);
  rB0 = *(const f32x4*)(wBase + gOff + 32);
  rB1 = *(const f32x4*)(wBase + gOff + 36);
  __syncthreads();

#pragma unroll 2
  for (int kt = 0; kt < NK; ++kt) {
    const int p = kt & 1;
    // stage tile kt+1 (in regs) into the other buffer; prefetch tile kt+2
    if (kt + 1 < NK) {
      {
        int4 a0, a1, a2;
        split8(rA0, rA1, a0, a1, a2);
        char* d = lds + (p ^ 1) * BUFS + wOff;
        *(int4*)(d) = a0; *(int4*)(d + LVS) = a1; *(int4*)(d + 2 * LVS) = a2;
      }
      {
        int4 b0, b1, b2;
        split8(rB0, rB1, b0, b1, b2);
        char* d = lds + (p ^ 1) * BUFS + MATS + wOff;
        *(int4*)(d) = b0; *(int4*)(d + LVS) = b1; *(int4*)(d + 2 * LVS) = b2;
      }
      if (kt + 2 < NK) {
        const size_t o = gOff + (size_t)(kt + 2) * 32;
        rA0 = *(const f32x4*)(aBase + o);
        rA1 = *(const f32x4*)(aBase + o + 4);
        rB0 = *(const f32x4*)(wBase + o);
        rB1 = *(const f32x4*)(wBase + o + 4);
      }
    }

    const char* rb = lds + p * BUFS;
    bfv8 bvv[2][3];
#pragma unroll
    for (int nt = 0; nt < 2; ++nt)
#pragma unroll
      for (int lv = 0; lv < 3; ++lv)
        bvv[nt][lv] = *(const bfv8*)(rb + frbB + nt * 256 + lv * LVS);

#pragma unroll
    for (int mt = 0; mt < 4; ++mt) {
      bfv8 a0 = *(const bfv8*)(rb + frbA + mt * 256);
      bfv8 a1 = *(const bfv8*)(rb + frbA + mt * 256 + LVS);
      bfv8 a2 = *(const bfv8*)(rb + frbA + mt * 256 + 2 * LVS);
#pragma unroll
      for (int nt = 0; nt < 2; ++nt) {
        Chi[mt][nt] = __builtin_amdgcn_mfma_f32_16x16x32_bf16(a0, bvv[nt][0], Chi[mt][nt], 0, 0, 0);
        Clo[mt][nt] = __builtin_amdgcn_mfma_f32_16x16x32_bf16(a0, bvv[nt][1], Clo[mt][nt], 0, 0, 0);
        Clo[mt][nt] = __builtin_amdgcn_mfma_f32_16x16x32_bf16(a1, bvv[nt][0], Clo[mt][nt], 0, 0, 0);
        Clo[mt][nt] = __builtin_amdgcn_mfma_f32_16x16x32_bf16(a1, bvv[nt][1], Clo[mt][nt], 0, 0, 0);
        Clo[mt][nt] = __builtin_amdgcn_mfma_f32_16x16x32_bf16(a0, bvv[nt][2], Clo[mt][nt], 0, 0, 0);
        Clo[mt][nt] = __builtin_amdgcn_mfma_f32_16x16x32_bf16(a2, bvv[nt][0], Clo[mt][nt], 0, 0, 0);
      }
    }

    if ((kt & 15) == 15) {   // flush chunk -> keeps fp32 accumulation walk ~1e-7
#pragma unroll
      for (int mt = 0; mt < 4; ++mt)
#pragma unroll
        for (int nt = 0; nt < 2; ++nt) {
          Ctot[mt][nt] += Chi[mt][nt];
          Chi[mt][nt] = f32x4{0.f, 0.f, 0.f, 0.f};
        }
    }
    __syncthreads();
  }

  // epilogue: C/D layout (verified): col = lane&15, row = (lane>>4)*4 + reg
  const int col = bn * 128 + wn * 32 + (lane & 15);
  const int row0 = bm * 128 + wm * 64 + ((lane >> 4) << 2);
#pragma unroll
  for (int mt = 0; mt < 4; ++mt)
#pragma unroll
    for (int nt = 0; nt < 2; ++nt) {
#pragma unroll
      for (int r = 0; r < 4; ++r) {
        float val = (float)((double)Ctot[mt][nt][r] + (double)Chi[mt][nt][r] +
                            (double)Clo[mt][nt][r]);
        C[(size_t)(row0 + mt * 16 + r) * NE + (col + nt * 16)] = val;
      }
    }
}

// One wave per token. Selection compares raw fp32 logits (sigmoid is monotone),
// packed as u64 = orderable(logit)<<32 | ~expert (jax tie-break: lower index).
// expf only for group sums (f64-summed) and the 8 output weights.
__global__ __launch_bounds__(256)
void router(const float* __restrict__ logits, float* __restrict__ out_w,
            float* __restrict__ out_i) {
  const int gid = blockIdx.x * blockDim.x + threadIdx.x;
  const int tok = gid >> 6;
  const int lane = gid & 63;
  if (tok >= TOK) return;

  const float4 v = *(const float4*)(logits + (size_t)tok * NE + lane * 4);
  float x[4] = {v.x, v.y, v.z, v.w};
  float s[4];
#pragma unroll
  for (int j = 0; j < 4; ++j) s[j] = 1.0f / (1.0f + __expf(-x[j]));

  // group sums: lanes [8g..8g+7] cover experts [32g..32g+31]
  double gsum = (double)s[0] + (double)s[1] + (double)s[2] + (double)s[3];
  gsum += __shfl_xor(gsum, 1);
  gsum += __shfl_xor(gsum, 2);
  gsum += __shfl_xor(gsum, 4);

  double gs[8];
#pragma unroll
  for (int g = 0; g < 8; ++g) gs[g] = __shfl(gsum, g * 8);

  unsigned sel = 0;
#pragma unroll
  for (int r = 0; r < 4; ++r) {
    int best = 0;
    double bv = -1e300;
#pragma unroll
    for (int g = 0; g < 8; ++g)
      if (!((sel >> g) & 1) && gs[g] > bv) { bv = gs[g]; best = g; }
    sel |= 1u << best;
  }

  const bool act = (sel >> (lane >> 3)) & 1;

  unsigned long long k[4];
#pragma unroll
  for (int j = 0; j < 4; ++j) {
    unsigned u = __float_as_uint(x[j]);
    unsigned fk = (u & 0x80000000u) ? ~u : (u | 0x80000000u);  // order-preserving
    unsigned e = (unsigned)(lane * 4 + j);
    k[j] = act ? (((unsigned long long)fk << 32) | (unsigned)(~e)) : 0ull;
  }

  unsigned long long win[8];
#pragma unroll
  for (int r = 0; r < 8; ++r) {
    unsigned long long lk01 = k[0] > k[1] ? k[0] : k[1];
    unsigned long long lk23 = k[2] > k[3] ? k[2] : k[3];
    unsigned long long lk = lk01 > lk23 ? lk01 : lk23;
#pragma unroll
    for (int off = 1; off < 64; off <<= 1) {
      unsigned long long o = __shfl_xor(lk, off);
      lk = o > lk ? o : lk;
    }
    win[r] = lk;
    const unsigned e = ~(unsigned)lk;          // recover expert index
    const bool own = (e >> 2) == (unsigned)lane;
#pragma unroll
    for (int j = 0; j < 4; ++j)
      if (own && (e & 3) == (unsigned)j) k[j] = 0ull;
  }

  // recompute winner scores (uniform across lanes; static indexing only)
  float wsc[8];
  float denom = 0.f;
#pragma unroll
  for (int r = 0; r < 8; ++r) {
    unsigned fk = (unsigned)(win[r] >> 32);
    unsigned u = (fk & 0x80000000u) ? (fk ^ 0x80000000u) : ~fk;
    float lg = __uint_as_float(u);
    wsc[r] = 1.0f / (1.0f + __expf(-lg));
    denom += wsc[r];
  }
  if (denom < 1e-12f) denom = 1e-12f;

  const size_t base = (size_t)tok * 8;
#pragma unroll
  for (int r = 0; r < 8; ++r)
    if (lane == r) {
      out_w[base + r] = wsc[r] / denom;
      out_i[base + r] = (float)(~(unsigned)win[r]);
    }
}

extern "C" void kernel_launch(void* const* d_in, const int* in_sizes, int n_in,
                              void* d_out, int out_size, void* d_ws, size_t ws_size,
                              hipStream_t stream) {
  const float* hs = (const float*)d_in[0];  // [16384, 7168]
  const float* W  = (const float*)d_in[1];  // [256, 7168]
  float* out = (float*)d_out;
  // d_out layout (read back as float32): weights [T,8] | indices [T,8] | logits [T,256]
  float* out_w   = out;
  float* out_i   = out + (size_t)TOK * 8;
  float* logitsO = out + (size_t)TOK * 16;

  gemm_split3<<<dim3(256), dim3(NTHR), 0, stream>>>(hs, W, logitsO);
  router<<<dim3(TOK * 64 / 256), dim3(256), 0, stream>>>(logitsO, out_w, out_i);
}